// Round 1
// baseline (948.748 us; speedup 1.0000x reference)
//
#include <hip/hip_runtime.h>
#include <float.h>

// ---------------- CSR build (by dst) ----------------

__global__ void hist_kernel(const int* __restrict__ dst, int E, int* __restrict__ cnt) {
    int e = blockIdx.x * blockDim.x + threadIdx.x;
    if (e < E) atomicAdd(&cnt[dst[e]], 1);
}

__global__ __launch_bounds__(1024) void scan_kernel(const int* __restrict__ cnt, int N,
                                                    int* __restrict__ row_start,
                                                    int* __restrict__ cursor) {
    __shared__ int sums[1024];
    int t = threadIdx.x;
    int chunk = (N + 1023) / 1024;
    int begin = t * chunk;
    int end = begin + chunk; if (end > N) end = N;
    int s = 0;
    for (int i = begin; i < end; ++i) s += cnt[i];
    sums[t] = s;
    __syncthreads();
    for (int off = 1; off < 1024; off <<= 1) {
        int v = (t >= off) ? sums[t - off] : 0;
        __syncthreads();
        sums[t] += v;
        __syncthreads();
    }
    int running = (t == 0) ? 0 : sums[t - 1];
    for (int i = begin; i < end; ++i) {
        row_start[i] = running;
        cursor[i]    = running;
        running += cnt[i];
    }
}

__global__ void fill_kernel(const int* __restrict__ src, const int* __restrict__ dst, int E,
                            int* __restrict__ cursor, int* __restrict__ col) {
    int e = blockIdx.x * blockDim.x + threadIdx.x;
    if (e < E) {
        int d = dst[e];
        int pos = atomicAdd(&cursor[d], 1);
        col[pos] = src[e];
    }
}

// ---------------- max aggregation: one wave per dst node ----------------

__global__ void agg_kernel(const float* __restrict__ xin,
                           const int* __restrict__ row_start, const int* __restrict__ cnt,
                           const int* __restrict__ col,
                           float* __restrict__ agg, int N) {
    int node = (blockIdx.x * blockDim.x + threadIdx.x) >> 6;
    int lane = threadIdx.x & 63;
    if (node >= N) return;
    int beg = row_start[node];
    int deg = cnt[node];
    float m0 = -FLT_MAX, m1 = -FLT_MAX;
    for (int j = 0; j < deg; ++j) {
        int s = col[beg + j];
        float2 v = *reinterpret_cast<const float2*>(&xin[(size_t)s * 128 + lane * 2]);
        m0 = fmaxf(m0, v.x);
        m1 = fmaxf(m1, v.y);
    }
    if (deg == 0) { m0 = 0.f; m1 = 0.f; }
    float2 o; o.x = m0; o.y = m1;
    *reinterpret_cast<float2*>(&agg[(size_t)node * 128 + lane * 2]) = o;
}

// ---------------- fused layer GEMM: relu(agg@Wn + x@Ws + b) ----------------
// BM=64 rows/block, BN=128 (full), BK=32, 256 threads, 8x4 outputs/thread.

__global__ __launch_bounds__(256) void layer_kernel(
    const float* __restrict__ agg, const float* __restrict__ xin,
    const float* __restrict__ Wn, const float* __restrict__ Wsf,
    const float* __restrict__ bias, float* __restrict__ xout, int N)
{
    __shared__ float As[64][36];   // +4 pad: kills 8-way bank conflict on stores
    __shared__ float Bs[32][128];
    int tid = threadIdx.x;
    int m0 = blockIdx.x * 64;
    int tc = tid & 31;   // output col group: cols tc*4 .. tc*4+3
    int tr = tid >> 5;   // 0..7: rows tr*8 .. tr*8+7

    float4 acc[8];
    #pragma unroll
    for (int r = 0; r < 8; ++r) acc[r] = make_float4(0.f, 0.f, 0.f, 0.f);

    for (int phase = 0; phase < 2; ++phase) {
        const float* A = phase ? xin : agg;
        const float* W = phase ? Wsf : Wn;
        for (int k0 = 0; k0 < 128; k0 += 32) {
            __syncthreads();
            // stage A tile: 64x32
            {
                int lr = tid >> 3;   // 0..31
                int lc = tid & 7;    // float4 col 0..7
                #pragma unroll
                for (int it = 0; it < 2; ++it) {
                    int r = lr + it * 32;
                    int gr = m0 + r;
                    float4 v = make_float4(0.f, 0.f, 0.f, 0.f);
                    if (gr < N)
                        v = *reinterpret_cast<const float4*>(&A[(size_t)gr * 128 + k0 + lc * 4]);
                    *reinterpret_cast<float4*>(&As[r][lc * 4]) = v;
                }
            }
            // stage W tile: 32x128
            {
                int lr = tid >> 5;   // 0..7
                int lc = tid & 31;   // float4 col 0..31
                #pragma unroll
                for (int it = 0; it < 4; ++it) {
                    int r = lr + it * 8;
                    *reinterpret_cast<float4*>(&Bs[r][lc * 4]) =
                        *reinterpret_cast<const float4*>(&W[(size_t)(k0 + r) * 128 + lc * 4]);
                }
            }
            __syncthreads();
            #pragma unroll
            for (int kk = 0; kk < 32; kk += 4) {
                float4 b0 = *reinterpret_cast<const float4*>(&Bs[kk + 0][tc * 4]);
                float4 b1 = *reinterpret_cast<const float4*>(&Bs[kk + 1][tc * 4]);
                float4 b2 = *reinterpret_cast<const float4*>(&Bs[kk + 2][tc * 4]);
                float4 b3 = *reinterpret_cast<const float4*>(&Bs[kk + 3][tc * 4]);
                #pragma unroll
                for (int rr = 0; rr < 8; ++rr) {
                    float4 a = *reinterpret_cast<const float4*>(&As[tr * 8 + rr][kk]);
                    acc[rr].x += a.x * b0.x + a.y * b1.x + a.z * b2.x + a.w * b3.x;
                    acc[rr].y += a.x * b0.y + a.y * b1.y + a.z * b2.y + a.w * b3.y;
                    acc[rr].z += a.x * b0.z + a.y * b1.z + a.z * b2.z + a.w * b3.z;
                    acc[rr].w += a.x * b0.w + a.y * b1.w + a.z * b2.w + a.w * b3.w;
                }
            }
        }
    }
    float4 bv = *reinterpret_cast<const float4*>(&bias[tc * 4]);
    #pragma unroll
    for (int rr = 0; rr < 8; ++rr) {
        int gr = m0 + tr * 8 + rr;
        if (gr < N) {
            float4 o;
            o.x = fmaxf(acc[rr].x + bv.x, 0.f);
            o.y = fmaxf(acc[rr].y + bv.y, 0.f);
            o.z = fmaxf(acc[rr].z + bv.z, 0.f);
            o.w = fmaxf(acc[rr].w + bv.w, 0.f);
            *reinterpret_cast<float4*>(&xout[(size_t)gr * 128 + tc * 4]) = o;
        }
    }
}

// ---------------- global max pool per graph ----------------

__global__ void pool_kernel(const float* __restrict__ x, const int* __restrict__ batch,
                            int N, float* __restrict__ pooled) {
    int g = blockIdx.x;
    int f = threadIdx.x;
    int lo = 0, hi = N;
    while (lo < hi) { int mid = (lo + hi) >> 1; if (batch[mid] < g) lo = mid + 1; else hi = mid; }
    int s = lo;
    hi = N;
    while (lo < hi) { int mid = (lo + hi) >> 1; if (batch[mid] < g + 1) lo = mid + 1; else hi = mid; }
    int e = lo;
    float m = 0.f;  // relu outputs are >= 0; empty segment -> 0 per reference
    for (int n = s; n < e; ++n) m = fmaxf(m, x[(size_t)n * 128 + f]);
    pooled[g * 128 + f] = m;
}

// ---------------- head: h = pooled@linW+linb ; out = h@outW+outb ----------------

__global__ __launch_bounds__(256) void head_kernel(
    const float* __restrict__ pooled,
    const float* __restrict__ linW, const float* __restrict__ linb,
    const float* __restrict__ outW, const float* __restrict__ outb,
    float* __restrict__ out)
{
    __shared__ float pl[128];
    __shared__ float hrow[256];
    int g = blockIdx.x, t = threadIdx.x;
    if (t < 128) pl[t] = pooled[g * 128 + t];
    __syncthreads();
    float acc = linb[t];
    for (int k = 0; k < 128; ++k) acc += pl[k] * linW[k * 256 + t];
    hrow[t] = acc;
    __syncthreads();
    if (t < 10) {
        float o = outb[t];
        for (int k = 0; k < 256; ++k) o += hrow[k] * outW[k * 10 + t];
        out[g * 10 + t] = o;
    }
}

// ---------------- launch ----------------

static inline size_t align_up(size_t v, size_t a) { return (v + a - 1) & ~(a - 1); }

extern "C" void kernel_launch(void* const* d_in, const int* in_sizes, int n_in,
                              void* d_out, int out_size, void* d_ws, size_t ws_size,
                              hipStream_t stream) {
    const float* x      = (const float*)d_in[0];
    const int*   ei     = (const int*)d_in[1];
    const int*   batch  = (const int*)d_in[2];
    const float* WsSelf = (const float*)d_in[3];
    const float* WsNei  = (const float*)d_in[4];
    const float* bsAll  = (const float*)d_in[5];
    const float* linW   = (const float*)d_in[6];
    const float* linb   = (const float*)d_in[7];
    const float* outW   = (const float*)d_in[8];
    const float* outb   = (const float*)d_in[9];

    const int N = in_sizes[0] / 128;
    const int E = in_sizes[1] / 2;
    const int L = in_sizes[3] / (128 * 128);
    const int* src = ei;
    const int* dst = ei + E;

    // workspace carve
    char* w = (char*)d_ws;
    int* cnt       = (int*)w;  w += align_up((size_t)N * 4, 256);
    int* row_start = (int*)w;  w += align_up((size_t)N * 4, 256);
    int* cursor    = (int*)w;  w += align_up((size_t)N * 4, 256);
    int* col       = (int*)w;  w += align_up((size_t)E * 4, 256);
    float* agg     = (float*)w; w += align_up((size_t)N * 128 * 4, 256);
    float* xa      = (float*)w; w += align_up((size_t)N * 128 * 4, 256);
    float* xb      = (float*)w; w += align_up((size_t)N * 128 * 4, 256);
    float* pooled  = (float*)w; w += align_up((size_t)64 * 128 * 4, 256);
    (void)ws_size;

    hipMemsetAsync(cnt, 0, (size_t)N * 4, stream);
    hist_kernel<<<(E + 255) / 256, 256, 0, stream>>>(dst, E, cnt);
    scan_kernel<<<1, 1024, 0, stream>>>(cnt, N, row_start, cursor);
    fill_kernel<<<(E + 255) / 256, 256, 0, stream>>>(src, dst, E, cursor, col);

    const float* xin = x;
    float* bufs[2] = { xa, xb };
    for (int l = 0; l < L; ++l) {
        agg_kernel<<<(N + 3) / 4, 256, 0, stream>>>(xin, row_start, cnt, col, agg, N);
        layer_kernel<<<(N + 63) / 64, 256, 0, stream>>>(
            agg, xin, WsNei + (size_t)l * 128 * 128, WsSelf + (size_t)l * 128 * 128,
            bsAll + (size_t)l * 128, bufs[l & 1], N);
        xin = bufs[l & 1];
    }

    pool_kernel<<<64, 128, 0, stream>>>(xin, batch, N, pooled);
    head_kernel<<<64, 256, 0, stream>>>(pooled, linW, linb, outW, outb, (float*)d_out);
}

// Round 2
// 784.526 us; speedup vs baseline: 1.2093x; 1.2093x over previous
//
#include <hip/hip_runtime.h>
#include <float.h>

// ---------------- CSR build (by dst) ----------------

__global__ void hist_kernel(const int* __restrict__ dst, int E, int* __restrict__ cnt) {
    int e = blockIdx.x * blockDim.x + threadIdx.x;
    if (e < E) atomicAdd(&cnt[dst[e]], 1);
}

__global__ __launch_bounds__(1024) void scan_kernel(const int* __restrict__ cnt, int N,
                                                    int* __restrict__ row_start,
                                                    int* __restrict__ cursor) {
    __shared__ int sums[1024];
    int t = threadIdx.x;
    int chunk = (N + 1023) / 1024;
    int begin = t * chunk;
    int end = begin + chunk; if (end > N) end = N;
    int s = 0;
    for (int i = begin; i < end; ++i) s += cnt[i];
    sums[t] = s;
    __syncthreads();
    for (int off = 1; off < 1024; off <<= 1) {
        int v = (t >= off) ? sums[t - off] : 0;
        __syncthreads();
        sums[t] += v;
        __syncthreads();
    }
    int running = (t == 0) ? 0 : sums[t - 1];
    for (int i = begin; i < end; ++i) {
        row_start[i] = running;
        cursor[i]    = running;
        running += cnt[i];
    }
}

__global__ void fill_kernel(const int* __restrict__ src, const int* __restrict__ dst, int E,
                            int* __restrict__ cursor, int* __restrict__ col) {
    int e = blockIdx.x * blockDim.x + threadIdx.x;
    if (e < E) {
        int d = dst[e];
        int pos = atomicAdd(&cursor[d], 1);
        col[pos] = src[e];
    }
}

// ---------------- max aggregation: 32 lanes per dst node, float4/lane ----------------

__global__ void agg_kernel(const float* __restrict__ xin,
                           const int* __restrict__ row_start, const int* __restrict__ cnt,
                           const int* __restrict__ col,
                           float* __restrict__ agg, int N) {
    int node = (blockIdx.x * blockDim.x + threadIdx.x) >> 5;
    int lane = threadIdx.x & 31;
    if (node >= N) return;
    int beg = row_start[node];
    int deg = cnt[node];
    float4 m = make_float4(-FLT_MAX, -FLT_MAX, -FLT_MAX, -FLT_MAX);
    for (int j = 0; j < deg; ++j) {
        int s = col[beg + j];
        float4 v = *reinterpret_cast<const float4*>(&xin[(size_t)s * 128 + lane * 4]);
        m.x = fmaxf(m.x, v.x);
        m.y = fmaxf(m.y, v.y);
        m.z = fmaxf(m.z, v.z);
        m.w = fmaxf(m.w, v.w);
    }
    if (deg == 0) m = make_float4(0.f, 0.f, 0.f, 0.f);
    *reinterpret_cast<float4*>(&agg[(size_t)node * 128 + lane * 4]) = m;
}

// ---------------- fused layer GEMM: relu(agg@Wn + x@Ws + b) ----------------
// BM=64 rows/block, BN=128 (full), BK=32, 256 threads, 8x4 outputs/thread.

__global__ __launch_bounds__(256) void layer_kernel(
    const float* __restrict__ agg, const float* __restrict__ xin,
    const float* __restrict__ Wn, const float* __restrict__ Wsf,
    const float* __restrict__ bias, float* __restrict__ xout, int N)
{
    __shared__ float As[64][36];   // +4 pad: kills 8-way bank conflict on stores
    __shared__ float Bs[32][128];
    int tid = threadIdx.x;
    int m0 = blockIdx.x * 64;
    int tc = tid & 31;   // output col group: cols tc*4 .. tc*4+3
    int tr = tid >> 5;   // 0..7: rows tr*8 .. tr*8+7

    float4 acc[8];
    #pragma unroll
    for (int r = 0; r < 8; ++r) acc[r] = make_float4(0.f, 0.f, 0.f, 0.f);

    for (int phase = 0; phase < 2; ++phase) {
        const float* A = phase ? xin : agg;
        const float* W = phase ? Wsf : Wn;
        for (int k0 = 0; k0 < 128; k0 += 32) {
            __syncthreads();
            // stage A tile: 64x32
            {
                int lr = tid >> 3;   // 0..31
                int lc = tid & 7;    // float4 col 0..7
                #pragma unroll
                for (int it = 0; it < 2; ++it) {
                    int r = lr + it * 32;
                    int gr = m0 + r;
                    float4 v = make_float4(0.f, 0.f, 0.f, 0.f);
                    if (gr < N)
                        v = *reinterpret_cast<const float4*>(&A[(size_t)gr * 128 + k0 + lc * 4]);
                    *reinterpret_cast<float4*>(&As[r][lc * 4]) = v;
                }
            }
            // stage W tile: 32x128
            {
                int lr = tid >> 5;   // 0..7
                int lc = tid & 31;   // float4 col 0..31
                #pragma unroll
                for (int it = 0; it < 4; ++it) {
                    int r = lr + it * 8;
                    *reinterpret_cast<float4*>(&Bs[r][lc * 4]) =
                        *reinterpret_cast<const float4*>(&W[(size_t)(k0 + r) * 128 + lc * 4]);
                }
            }
            __syncthreads();
            #pragma unroll
            for (int kk = 0; kk < 32; kk += 4) {
                float4 b0 = *reinterpret_cast<const float4*>(&Bs[kk + 0][tc * 4]);
                float4 b1 = *reinterpret_cast<const float4*>(&Bs[kk + 1][tc * 4]);
                float4 b2 = *reinterpret_cast<const float4*>(&Bs[kk + 2][tc * 4]);
                float4 b3 = *reinterpret_cast<const float4*>(&Bs[kk + 3][tc * 4]);
                #pragma unroll
                for (int rr = 0; rr < 8; ++rr) {
                    float4 a = *reinterpret_cast<const float4*>(&As[tr * 8 + rr][kk]);
                    acc[rr].x += a.x * b0.x + a.y * b1.x + a.z * b2.x + a.w * b3.x;
                    acc[rr].y += a.x * b0.y + a.y * b1.y + a.z * b2.y + a.w * b3.y;
                    acc[rr].z += a.x * b0.z + a.y * b1.z + a.z * b2.z + a.w * b3.z;
                    acc[rr].w += a.x * b0.w + a.y * b1.w + a.z * b2.w + a.w * b3.w;
                }
            }
        }
    }
    float4 bv = *reinterpret_cast<const float4*>(&bias[tc * 4]);
    #pragma unroll
    for (int rr = 0; rr < 8; ++rr) {
        int gr = m0 + tr * 8 + rr;
        if (gr < N) {
            float4 o;
            o.x = fmaxf(acc[rr].x + bv.x, 0.f);
            o.y = fmaxf(acc[rr].y + bv.y, 0.f);
            o.z = fmaxf(acc[rr].z + bv.z, 0.f);
            o.w = fmaxf(acc[rr].w + bv.w, 0.f);
            *reinterpret_cast<float4*>(&xout[(size_t)gr * 128 + tc * 4]) = o;
        }
    }
}

// ---------------- global max pool per graph: chunked + atomicMax ----------------
// Post-relu values are >= 0, so float max == uint-bit max and empty segments
// stay at the 0-initialized value (matches reference's empty->0 convention).

#define POOL_CHUNK 128

__global__ __launch_bounds__(128) void pool_kernel(const float* __restrict__ x,
                                                   const int* __restrict__ batch,
                                                   int N,
                                                   unsigned int* __restrict__ pooled) {
    int f = threadIdx.x;            // feature 0..127
    int n0 = blockIdx.x * POOL_CHUNK;
    if (n0 >= N) return;
    int n1 = n0 + POOL_CHUNK; if (n1 > N) n1 = N;
    int g = batch[n0];
    float m = 0.f;
    for (int n = n0; n < n1; ++n) {
        int bg = batch[n];
        if (bg != g) {
            atomicMax(&pooled[g * 128 + f], __float_as_uint(m));
            m = 0.f; g = bg;
        }
        m = fmaxf(m, x[(size_t)n * 128 + f]);
    }
    atomicMax(&pooled[g * 128 + f], __float_as_uint(m));
}

// ---------------- head: h = pooled@linW+linb ; out = h@outW+outb ----------------

__global__ __launch_bounds__(256) void head_kernel(
    const float* __restrict__ pooled,
    const float* __restrict__ linW, const float* __restrict__ linb,
    const float* __restrict__ outW, const float* __restrict__ outb,
    float* __restrict__ out)
{
    __shared__ float pl[128];
    __shared__ float hrow[256];
    int g = blockIdx.x, t = threadIdx.x;
    if (t < 128) pl[t] = pooled[g * 128 + t];
    __syncthreads();
    float acc = linb[t];
    for (int k = 0; k < 128; ++k) acc += pl[k] * linW[k * 256 + t];
    hrow[t] = acc;
    __syncthreads();
    if (t < 10) {
        float o = outb[t];
        for (int k = 0; k < 256; ++k) o += hrow[k] * outW[k * 10 + t];
        out[g * 10 + t] = o;
    }
}

// ---------------- launch ----------------

static inline size_t align_up(size_t v, size_t a) { return (v + a - 1) & ~(a - 1); }

extern "C" void kernel_launch(void* const* d_in, const int* in_sizes, int n_in,
                              void* d_out, int out_size, void* d_ws, size_t ws_size,
                              hipStream_t stream) {
    const float* x      = (const float*)d_in[0];
    const int*   ei     = (const int*)d_in[1];
    const int*   batch  = (const int*)d_in[2];
    const float* WsSelf = (const float*)d_in[3];
    const float* WsNei  = (const float*)d_in[4];
    const float* bsAll  = (const float*)d_in[5];
    const float* linW   = (const float*)d_in[6];
    const float* linb   = (const float*)d_in[7];
    const float* outW   = (const float*)d_in[8];
    const float* outb   = (const float*)d_in[9];

    const int N = in_sizes[0] / 128;
    const int E = in_sizes[1] / 2;
    const int L = in_sizes[3] / (128 * 128);
    const int* src = ei;
    const int* dst = ei + E;

    // workspace carve
    char* w = (char*)d_ws;
    int* cnt       = (int*)w;  w += align_up((size_t)N * 4, 256);
    int* row_start = (int*)w;  w += align_up((size_t)N * 4, 256);
    int* cursor    = (int*)w;  w += align_up((size_t)N * 4, 256);
    int* col       = (int*)w;  w += align_up((size_t)E * 4, 256);
    float* agg     = (float*)w; w += align_up((size_t)N * 128 * 4, 256);
    float* xa      = (float*)w; w += align_up((size_t)N * 128 * 4, 256);
    float* xb      = (float*)w; w += align_up((size_t)N * 128 * 4, 256);
    float* pooled  = (float*)w; w += align_up((size_t)64 * 128 * 4, 256);
    (void)ws_size;

    hipMemsetAsync(cnt, 0, (size_t)N * 4, stream);
    hipMemsetAsync(pooled, 0, (size_t)64 * 128 * 4, stream);
    hist_kernel<<<(E + 255) / 256, 256, 0, stream>>>(dst, E, cnt);
    scan_kernel<<<1, 1024, 0, stream>>>(cnt, N, row_start, cursor);
    fill_kernel<<<(E + 255) / 256, 256, 0, stream>>>(src, dst, E, cursor, col);

    const float* xin = x;
    float* bufs[2] = { xa, xb };
    for (int l = 0; l < L; ++l) {
        agg_kernel<<<(N * 32 + 255) / 256, 256, 0, stream>>>(xin, row_start, cnt, col, agg, N);
        layer_kernel<<<(N + 63) / 64, 256, 0, stream>>>(
            agg, xin, WsNei + (size_t)l * 128 * 128, WsSelf + (size_t)l * 128 * 128,
            bsAll + (size_t)l * 128, bufs[l & 1], N);
        xin = bufs[l & 1];
    }

    pool_kernel<<<(N + POOL_CHUNK - 1) / POOL_CHUNK, 128, 0, stream>>>(
        xin, batch, N, (unsigned int*)pooled);
    head_kernel<<<64, 256, 0, stream>>>(pooled, linW, linb, outW, outb, (float*)d_out);
}

// Round 3
// 563.212 us; speedup vs baseline: 1.6845x; 1.3930x over previous
//
#include <hip/hip_runtime.h>
#include <float.h>

typedef __bf16 bf16x8 __attribute__((ext_vector_type(8)));
typedef float f32x4 __attribute__((ext_vector_type(4)));
typedef unsigned short ushort8 __attribute__((ext_vector_type(8)));

__device__ inline unsigned short f2bh(float f) {
    unsigned int u = __float_as_uint(f);
    return (unsigned short)((u + 0x7FFFu + ((u >> 16) & 1u)) >> 16);
}
__device__ inline float bh2f(unsigned short h) {
    return __uint_as_float((unsigned int)h << 16);
}

// ---------------- CSR build (by dst) ----------------

__global__ void hist_kernel(const int* __restrict__ dst, int E, int* __restrict__ cnt) {
    int e = blockIdx.x * blockDim.x + threadIdx.x;
    if (e < E) atomicAdd(&cnt[dst[e]], 1);
}

__global__ __launch_bounds__(1024) void scan_kernel(const int* __restrict__ cnt, int N,
                                                    int* __restrict__ row_start,
                                                    int* __restrict__ cursor) {
    __shared__ int sums[1024];
    int t = threadIdx.x;
    int chunk = (N + 1023) / 1024;
    int begin = t * chunk;
    int end = begin + chunk; if (end > N) end = N;
    int s = 0;
    for (int i = begin; i < end; ++i) s += cnt[i];
    sums[t] = s;
    __syncthreads();
    for (int off = 1; off < 1024; off <<= 1) {
        int v = (t >= off) ? sums[t - off] : 0;
        __syncthreads();
        sums[t] += v;
        __syncthreads();
    }
    int running = (t == 0) ? 0 : sums[t - 1];
    for (int i = begin; i < end; ++i) {
        row_start[i] = running;
        cursor[i]    = running;
        running += cnt[i];
    }
}

__global__ void fill_kernel(const int* __restrict__ src, const int* __restrict__ dst, int E,
                            int* __restrict__ cursor, int* __restrict__ col) {
    int e = blockIdx.x * blockDim.x + threadIdx.x;
    if (e < E) {
        int d = dst[e];
        int pos = atomicAdd(&cursor[d], 1);
        col[pos] = src[e];
    }
}

// ---------------- max aggregation: 32 lanes per dst node, float4/lane ----------------

__global__ void agg_kernel(const float* __restrict__ xin,
                           const int* __restrict__ row_start, const int* __restrict__ cnt,
                           const int* __restrict__ col,
                           float* __restrict__ agg, int N) {
    int node = (blockIdx.x * blockDim.x + threadIdx.x) >> 5;
    int lane = threadIdx.x & 31;
    if (node >= N) return;
    int beg = row_start[node];
    int deg = cnt[node];
    float4 m = make_float4(-FLT_MAX, -FLT_MAX, -FLT_MAX, -FLT_MAX);
    for (int j = 0; j < deg; ++j) {
        int s = col[beg + j];
        float4 v = *reinterpret_cast<const float4*>(&xin[(size_t)s * 128 + lane * 4]);
        m.x = fmaxf(m.x, v.x);
        m.y = fmaxf(m.y, v.y);
        m.z = fmaxf(m.z, v.z);
        m.w = fmaxf(m.w, v.w);
    }
    if (deg == 0) m = make_float4(0.f, 0.f, 0.f, 0.f);
    *reinterpret_cast<float4*>(&agg[(size_t)node * 128 + lane * 4]) = m;
}

// ---------------- W prep: split fp32 W into bf16 hi/lo, fragment-ordered ----------------
// dest layout per layer: [phase(2)][kgroup(16)][col(128)][j(8)]; phase0=Wnei, phase1=Wself.

__global__ void wprep_kernel(const float* __restrict__ Wn, const float* __restrict__ Wsf,
                             int total, unsigned short* __restrict__ Wfh,
                             unsigned short* __restrict__ Wfl) {
    int idx = blockIdx.x * blockDim.x + threadIdx.x;
    if (idx >= total) return;
    int c = idx & 127;
    int k = (idx >> 7) & 127;
    int p = (idx >> 14) & 1;
    int l = idx >> 15;
    const float* W = p ? Wsf : Wn;
    float v = W[(size_t)l * 16384 + k * 128 + c];
    unsigned short hi = f2bh(v);
    unsigned short lo = f2bh(v - bh2f(hi));
    size_t d = ((((size_t)l * 2 + p) * 16 + (k >> 3)) * 128 + c) * 8 + (k & 7);
    Wfh[d] = hi;
    Wfl[d] = lo;
}

// ---------------- fused layer GEMM via MFMA: relu([agg|x]@[Wn;Ws] + b) ----------------
// 256 threads = 4 waves; wave owns 32 rows x 128 cols; no LDS, no barriers.
// 3-term split-bf16: acc += Ah@Wh + Al@Wh + Ah@Wl  (~fp32 accuracy).

__global__ __launch_bounds__(256) void layer_mfma(
    const float* __restrict__ agg, const float* __restrict__ xin,
    const unsigned short* __restrict__ Wfh, const unsigned short* __restrict__ Wfl,
    const float* __restrict__ bias, float* __restrict__ xout, int N)
{
    const int lane = threadIdx.x & 63;
    const int wid  = threadIdx.x >> 6;
    const int l15  = lane & 15;
    const int lg   = lane >> 4;            // 0..3
    const int row0 = blockIdx.x * 128 + wid * 32;

    f32x4 acc[2][8];
    #pragma unroll
    for (int rt = 0; rt < 2; ++rt)
        #pragma unroll
        for (int nt = 0; nt < 8; ++nt) {
            f32x4 z = {0.f, 0.f, 0.f, 0.f};
            acc[rt][nt] = z;
        }

    int r0c = row0 + l15;      if (r0c > N - 1) r0c = N - 1;
    int r1c = row0 + 16 + l15; if (r1c > N - 1) r1c = N - 1;

    #pragma unroll
    for (int p = 0; p < 2; ++p) {
        const float* A = p ? xin : agg;
        const unsigned short* whb = Wfh + p * 16384 + ((size_t)(lg * 128 + l15)) * 8;
        const unsigned short* wlb = Wfl + p * 16384 + ((size_t)(lg * 128 + l15)) * 8;
        const float* a0 = A + (size_t)r0c * 128 + lg * 8;
        const float* a1 = A + (size_t)r1c * 128 + lg * 8;
        #pragma unroll
        for (int ks = 0; ks < 4; ++ks) {
            bf16x8 ah[2], al[2];
            #pragma unroll
            for (int rt = 0; rt < 2; ++rt) {
                const float* ap = (rt ? a1 : a0) + ks * 32;
                float4 v0 = *reinterpret_cast<const float4*>(ap);
                float4 v1 = *reinterpret_cast<const float4*>(ap + 4);
                float vv[8] = {v0.x, v0.y, v0.z, v0.w, v1.x, v1.y, v1.z, v1.w};
                ushort8 hh, ll;
                #pragma unroll
                for (int j = 0; j < 8; ++j) {
                    unsigned short h = f2bh(vv[j]);
                    hh[j] = h;
                    ll[j] = f2bh(vv[j] - bh2f(h));
                }
                ah[rt] = __builtin_bit_cast(bf16x8, hh);
                al[rt] = __builtin_bit_cast(bf16x8, ll);
            }
            const unsigned short* whk = whb + ks * 4096;
            const unsigned short* wlk = wlb + ks * 4096;
            #pragma unroll
            for (int nt = 0; nt < 8; ++nt) {
                bf16x8 bh = *reinterpret_cast<const bf16x8*>(whk + nt * 128);
                bf16x8 bl = *reinterpret_cast<const bf16x8*>(wlk + nt * 128);
                acc[0][nt] = __builtin_amdgcn_mfma_f32_16x16x32_bf16(ah[0], bh, acc[0][nt], 0, 0, 0);
                acc[1][nt] = __builtin_amdgcn_mfma_f32_16x16x32_bf16(ah[1], bh, acc[1][nt], 0, 0, 0);
                acc[0][nt] = __builtin_amdgcn_mfma_f32_16x16x32_bf16(al[0], bh, acc[0][nt], 0, 0, 0);
                acc[1][nt] = __builtin_amdgcn_mfma_f32_16x16x32_bf16(al[1], bh, acc[1][nt], 0, 0, 0);
                acc[0][nt] = __builtin_amdgcn_mfma_f32_16x16x32_bf16(ah[0], bl, acc[0][nt], 0, 0, 0);
                acc[1][nt] = __builtin_amdgcn_mfma_f32_16x16x32_bf16(ah[1], bl, acc[1][nt], 0, 0, 0);
            }
        }
    }

    #pragma unroll
    for (int nt = 0; nt < 8; ++nt) {
        float bv = bias[nt * 16 + l15];
        #pragma unroll
        for (int rt = 0; rt < 2; ++rt) {
            #pragma unroll
            for (int rr = 0; rr < 4; ++rr) {
                int row = row0 + rt * 16 + lg * 4 + rr;
                if (row < N) {
                    float o = fmaxf(acc[rt][nt][rr] + bv, 0.f);
                    xout[(size_t)row * 128 + nt * 16 + l15] = o;
                }
            }
        }
    }
}

// ---------------- global max pool per graph: chunked + atomicMax ----------------

#define POOL_CHUNK 128

__global__ __launch_bounds__(128) void pool_kernel(const float* __restrict__ x,
                                                   const int* __restrict__ batch,
                                                   int N,
                                                   unsigned int* __restrict__ pooled) {
    int f = threadIdx.x;
    int n0 = blockIdx.x * POOL_CHUNK;
    if (n0 >= N) return;
    int n1 = n0 + POOL_CHUNK; if (n1 > N) n1 = N;
    int g = batch[n0];
    float m = 0.f;
    for (int n = n0; n < n1; ++n) {
        int bg = batch[n];
        if (bg != g) {
            atomicMax(&pooled[g * 128 + f], __float_as_uint(m));
            m = 0.f; g = bg;
        }
        m = fmaxf(m, x[(size_t)n * 128 + f]);
    }
    atomicMax(&pooled[g * 128 + f], __float_as_uint(m));
}

// ---------------- head ----------------

__global__ __launch_bounds__(256) void head_kernel(
    const float* __restrict__ pooled,
    const float* __restrict__ linW, const float* __restrict__ linb,
    const float* __restrict__ outW, const float* __restrict__ outb,
    float* __restrict__ out)
{
    __shared__ float pl[128];
    __shared__ float hrow[256];
    int g = blockIdx.x, t = threadIdx.x;
    if (t < 128) pl[t] = pooled[g * 128 + t];
    __syncthreads();
    float acc = linb[t];
    for (int k = 0; k < 128; ++k) acc += pl[k] * linW[k * 256 + t];
    hrow[t] = acc;
    __syncthreads();
    if (t < 10) {
        float o = outb[t];
        for (int k = 0; k < 256; ++k) o += hrow[k] * outW[k * 10 + t];
        out[g * 10 + t] = o;
    }
}

// ---------------- launch ----------------

static inline size_t align_up(size_t v, size_t a) { return (v + a - 1) & ~(a - 1); }

extern "C" void kernel_launch(void* const* d_in, const int* in_sizes, int n_in,
                              void* d_out, int out_size, void* d_ws, size_t ws_size,
                              hipStream_t stream) {
    const float* x      = (const float*)d_in[0];
    const int*   ei     = (const int*)d_in[1];
    const int*   batch  = (const int*)d_in[2];
    const float* WsSelf = (const float*)d_in[3];
    const float* WsNei  = (const float*)d_in[4];
    const float* bsAll  = (const float*)d_in[5];
    const float* linW   = (const float*)d_in[6];
    const float* linb   = (const float*)d_in[7];
    const float* outW   = (const float*)d_in[8];
    const float* outb   = (const float*)d_in[9];

    const int N = in_sizes[0] / 128;
    const int E = in_sizes[1] / 2;
    const int L = in_sizes[3] / (128 * 128);
    const int* src = ei;
    const int* dst = ei + E;

    // workspace carve
    char* w = (char*)d_ws;
    int* cnt       = (int*)w;  w += align_up((size_t)N * 4, 256);
    int* row_start = (int*)w;  w += align_up((size_t)N * 4, 256);
    int* cursor    = (int*)w;  w += align_up((size_t)N * 4, 256);
    int* col       = (int*)w;  w += align_up((size_t)E * 4, 256);
    float* agg     = (float*)w; w += align_up((size_t)N * 128 * 4, 256);
    float* xa      = (float*)w; w += align_up((size_t)N * 128 * 4, 256);
    float* xb      = (float*)w; w += align_up((size_t)N * 128 * 4, 256);
    float* pooled  = (float*)w; w += align_up((size_t)64 * 128 * 4, 256);
    unsigned short* Wfh = (unsigned short*)w; w += align_up((size_t)L * 2 * 16384 * 2, 256);
    unsigned short* Wfl = (unsigned short*)w; w += align_up((size_t)L * 2 * 16384 * 2, 256);
    (void)ws_size;

    hipMemsetAsync(cnt, 0, (size_t)N * 4, stream);
    hipMemsetAsync(pooled, 0, (size_t)64 * 128 * 4, stream);

    const int wtotal = L * 2 * 128 * 128;
    wprep_kernel<<<(wtotal + 255) / 256, 256, 0, stream>>>(WsNei, WsSelf, wtotal, Wfh, Wfl);

    hist_kernel<<<(E + 255) / 256, 256, 0, stream>>>(dst, E, cnt);
    scan_kernel<<<1, 1024, 0, stream>>>(cnt, N, row_start, cursor);
    fill_kernel<<<(E + 255) / 256, 256, 0, stream>>>(src, dst, E, cursor, col);

    const float* xin = x;
    float* bufs[2] = { xa, xb };
    for (int l = 0; l < L; ++l) {
        agg_kernel<<<(N * 32 + 255) / 256, 256, 0, stream>>>(xin, row_start, cnt, col, agg, N);
        layer_mfma<<<(N + 127) / 128, 256, 0, stream>>>(
            agg, xin,
            Wfh + (size_t)l * 2 * 16384, Wfl + (size_t)l * 2 * 16384,
            bsAll + (size_t)l * 128, bufs[l & 1], N);
        xin = bufs[l & 1];
    }

    pool_kernel<<<(N + POOL_CHUNK - 1) / POOL_CHUNK, 128, 0, stream>>>(
        xin, batch, N, (unsigned int*)pooled);
    head_kernel<<<64, 256, 0, stream>>>(pooled, linW, linb, outW, outb, (float*)d_out);
}

// Round 4
// 473.276 us; speedup vs baseline: 2.0046x; 1.1900x over previous
//
#include <hip/hip_runtime.h>
#include <float.h>

typedef __bf16 bf16x8 __attribute__((ext_vector_type(8)));
typedef float f32x4 __attribute__((ext_vector_type(4)));
typedef unsigned short ushort8 __attribute__((ext_vector_type(8)));
typedef _Float16 h8 __attribute__((ext_vector_type(8)));
typedef _Float16 h4 __attribute__((ext_vector_type(4)));

__device__ inline unsigned short f2bh(float f) {
    unsigned int u = __float_as_uint(f);
    return (unsigned short)((u + 0x7FFFu + ((u >> 16) & 1u)) >> 16);
}
__device__ inline float bh2f(unsigned short h) {
    return __uint_as_float((unsigned int)h << 16);
}

// ---------------- fp32 -> fp16 convert (input x once per launch) ----------------

__global__ void cvt16_kernel(const float* __restrict__ xin, _Float16* __restrict__ x16,
                             int total8) {
    int i = blockIdx.x * blockDim.x + threadIdx.x;
    if (i >= total8) return;
    const float4* p = reinterpret_cast<const float4*>(xin + (size_t)i * 8);
    float4 a = p[0], b = p[1];
    h8 o;
    o[0] = (_Float16)a.x; o[1] = (_Float16)a.y; o[2] = (_Float16)a.z; o[3] = (_Float16)a.w;
    o[4] = (_Float16)b.x; o[5] = (_Float16)b.y; o[6] = (_Float16)b.z; o[7] = (_Float16)b.w;
    *reinterpret_cast<h8*>(x16 + (size_t)i * 8) = o;
}

// ---------------- CSR build (by dst): hist + 3-phase parallel scan + fill ----------------

__global__ void hist_kernel(const int* __restrict__ dst, int E, int* __restrict__ cnt) {
    int e = blockIdx.x * blockDim.x + threadIdx.x;
    if (e < E) atomicAdd(&cnt[dst[e]], 1);
}

__global__ __launch_bounds__(256) void bsum_kernel(const int* __restrict__ cnt, int N,
                                                   int* __restrict__ bsum) {
    __shared__ int red[256];
    int t = threadIdx.x;
    int i = blockIdx.x * 256 + t;
    red[t] = (i < N) ? cnt[i] : 0;
    __syncthreads();
    for (int off = 128; off > 0; off >>= 1) {
        if (t < off) red[t] += red[t + off];
        __syncthreads();
    }
    if (t == 0) bsum[blockIdx.x] = red[0];
}

__global__ __launch_bounds__(256) void bscan_kernel(const int* __restrict__ bsum, int nb,
                                                    int* __restrict__ boff) {
    __shared__ int s[256];
    int t = threadIdx.x;
    int v = (t < nb) ? bsum[t] : 0;
    s[t] = v;
    __syncthreads();
    for (int off = 1; off < 256; off <<= 1) {
        int u = (t >= off) ? s[t - off] : 0;
        __syncthreads();
        s[t] += u;
        __syncthreads();
    }
    if (t < nb) boff[t] = s[t] - v;   // exclusive block offset
}

__global__ __launch_bounds__(256) void scan_apply_kernel(const int* __restrict__ cnt, int N,
                                                         const int* __restrict__ boff,
                                                         int* __restrict__ row_start,
                                                         int* __restrict__ cursor) {
    __shared__ int s[256];
    int t = threadIdx.x;
    int i = blockIdx.x * 256 + t;
    int v = (i < N) ? cnt[i] : 0;
    s[t] = v;
    __syncthreads();
    for (int off = 1; off < 256; off <<= 1) {
        int u = (t >= off) ? s[t - off] : 0;
        __syncthreads();
        s[t] += u;
        __syncthreads();
    }
    int excl = boff[blockIdx.x] + s[t] - v;
    if (i < N) { row_start[i] = excl; cursor[i] = excl; }
}

__global__ void fill_kernel(const int* __restrict__ src, const int* __restrict__ dst, int E,
                            int* __restrict__ cursor, int* __restrict__ col) {
    int e = blockIdx.x * blockDim.x + threadIdx.x;
    if (e < E) {
        int d = dst[e];
        int pos = atomicAdd(&cursor[d], 1);
        col[pos] = src[e];
    }
}

// ---------------- max aggregation (fp16): 32 lanes/node, 4 halves/lane ----------------
// fp16 RTNE is monotone, so max in fp16 == fp16 of max; no extra error beyond
// the per-layer fp16 quantization of the activation chain.

__global__ void agg_kernel(const _Float16* __restrict__ x16,
                           const int* __restrict__ row_start, const int* __restrict__ cnt,
                           const int* __restrict__ col,
                           _Float16* __restrict__ agg16, int N) {
    int node = (blockIdx.x * blockDim.x + threadIdx.x) >> 5;
    int lane = threadIdx.x & 31;
    if (node >= N) return;
    int beg = row_start[node];
    int deg = cnt[node];
    const _Float16 NEG = (_Float16)(-65504.0f);
    _Float16 m0 = NEG, m1 = NEG, m2 = NEG, m3 = NEG;
    for (int j = 0; j < deg; ++j) {
        int s = col[beg + j];
        h4 v = *reinterpret_cast<const h4*>(&x16[(size_t)s * 128 + lane * 4]);
        m0 = v[0] > m0 ? v[0] : m0;
        m1 = v[1] > m1 ? v[1] : m1;
        m2 = v[2] > m2 ? v[2] : m2;
        m3 = v[3] > m3 ? v[3] : m3;
    }
    if (deg == 0) { m0 = (_Float16)0.f; m1 = (_Float16)0.f; m2 = (_Float16)0.f; m3 = (_Float16)0.f; }
    h4 o; o[0] = m0; o[1] = m1; o[2] = m2; o[3] = m3;
    *reinterpret_cast<h4*>(&agg16[(size_t)node * 128 + lane * 4]) = o;
}

// ---------------- W prep: split fp32 W into bf16 hi/lo, fragment-ordered ----------------
// dest layout per layer: [phase(2)][kgroup(16)][col(128)][j(8)]; phase0=Wnei, phase1=Wself.

__global__ void wprep_kernel(const float* __restrict__ Wn, const float* __restrict__ Wsf,
                             int total, unsigned short* __restrict__ Wfh,
                             unsigned short* __restrict__ Wfl) {
    int idx = blockIdx.x * blockDim.x + threadIdx.x;
    if (idx >= total) return;
    int c = idx & 127;
    int k = (idx >> 7) & 127;
    int p = (idx >> 14) & 1;
    int l = idx >> 15;
    const float* W = p ? Wsf : Wn;
    float v = W[(size_t)l * 16384 + k * 128 + c];
    unsigned short hi = f2bh(v);
    unsigned short lo = f2bh(v - bh2f(hi));
    size_t d = ((((size_t)l * 2 + p) * 16 + (k >> 3)) * 128 + c) * 8 + (k & 7);
    Wfh[d] = hi;
    Wfl[d] = lo;
}

// ---------------- fused layer GEMM via MFMA: relu([agg|x]@[Wn;Ws] + b) ----------------
// fp16 A operands split EXACTLY into bf16 hi+lo (11 <= 8+3 mantissa bits), so the
// 3-term trick (Ah@Wh + Al@Wh + Ah@Wl) reproduces the fp16-input GEMM at ~fp32 accuracy.

__global__ __launch_bounds__(256) void layer_mfma(
    const _Float16* __restrict__ agg16, const _Float16* __restrict__ xin16,
    const unsigned short* __restrict__ Wfh, const unsigned short* __restrict__ Wfl,
    const float* __restrict__ bias, _Float16* __restrict__ xout16, int N)
{
    const int lane = threadIdx.x & 63;
    const int wid  = threadIdx.x >> 6;
    const int l15  = lane & 15;
    const int lg   = lane >> 4;            // 0..3
    const int row0 = blockIdx.x * 128 + wid * 32;

    f32x4 acc[2][8];
    #pragma unroll
    for (int rt = 0; rt < 2; ++rt)
        #pragma unroll
        for (int nt = 0; nt < 8; ++nt) {
            f32x4 z = {0.f, 0.f, 0.f, 0.f};
            acc[rt][nt] = z;
        }

    int r0c = row0 + l15;      if (r0c > N - 1) r0c = N - 1;
    int r1c = row0 + 16 + l15; if (r1c > N - 1) r1c = N - 1;

    #pragma unroll
    for (int p = 0; p < 2; ++p) {
        const _Float16* A = p ? xin16 : agg16;
        const unsigned short* whb = Wfh + p * 16384 + ((size_t)(lg * 128 + l15)) * 8;
        const unsigned short* wlb = Wfl + p * 16384 + ((size_t)(lg * 128 + l15)) * 8;
        const _Float16* a0 = A + (size_t)r0c * 128 + lg * 8;
        const _Float16* a1 = A + (size_t)r1c * 128 + lg * 8;
        #pragma unroll
        for (int ks = 0; ks < 4; ++ks) {
            bf16x8 ah[2], al[2];
            #pragma unroll
            for (int rt = 0; rt < 2; ++rt) {
                const _Float16* ap = (rt ? a1 : a0) + ks * 32;
                h8 av = *reinterpret_cast<const h8*>(ap);
                ushort8 hh, ll;
                #pragma unroll
                for (int j = 0; j < 8; ++j) {
                    float f = (float)av[j];
                    unsigned short hi = f2bh(f);
                    float r = f - bh2f(hi);          // exactly representable in bf16
                    hh[j] = hi;
                    ll[j] = (unsigned short)(__float_as_uint(r) >> 16);
                }
                ah[rt] = __builtin_bit_cast(bf16x8, hh);
                al[rt] = __builtin_bit_cast(bf16x8, ll);
            }
            const unsigned short* whk = whb + ks * 4096;
            const unsigned short* wlk = wlb + ks * 4096;
            #pragma unroll
            for (int nt = 0; nt < 8; ++nt) {
                bf16x8 bh = *reinterpret_cast<const bf16x8*>(whk + nt * 128);
                bf16x8 bl = *reinterpret_cast<const bf16x8*>(wlk + nt * 128);
                acc[0][nt] = __builtin_amdgcn_mfma_f32_16x16x32_bf16(ah[0], bh, acc[0][nt], 0, 0, 0);
                acc[1][nt] = __builtin_amdgcn_mfma_f32_16x16x32_bf16(ah[1], bh, acc[1][nt], 0, 0, 0);
                acc[0][nt] = __builtin_amdgcn_mfma_f32_16x16x32_bf16(al[0], bh, acc[0][nt], 0, 0, 0);
                acc[1][nt] = __builtin_amdgcn_mfma_f32_16x16x32_bf16(al[1], bh, acc[1][nt], 0, 0, 0);
                acc[0][nt] = __builtin_amdgcn_mfma_f32_16x16x32_bf16(ah[0], bl, acc[0][nt], 0, 0, 0);
                acc[1][nt] = __builtin_amdgcn_mfma_f32_16x16x32_bf16(ah[1], bl, acc[1][nt], 0, 0, 0);
            }
        }
    }

    #pragma unroll
    for (int nt = 0; nt < 8; ++nt) {
        float bv = bias[nt * 16 + l15];
        #pragma unroll
        for (int rt = 0; rt < 2; ++rt) {
            #pragma unroll
            for (int rr = 0; rr < 4; ++rr) {
                int row = row0 + rt * 16 + lg * 4 + rr;
                if (row < N) {
                    float o = fmaxf(acc[rt][nt][rr] + bv, 0.f);
                    xout16[(size_t)row * 128 + nt * 16 + l15] = (_Float16)o;
                }
            }
        }
    }
}

// ---------------- global max pool per graph: chunked + atomicMax ----------------
// Post-relu values >= 0, so float max == uint-bit max; empty segments stay 0.

#define POOL_CHUNK 128

__global__ __launch_bounds__(128) void pool_kernel(const _Float16* __restrict__ x16,
                                                   const int* __restrict__ batch,
                                                   int N,
                                                   unsigned int* __restrict__ pooled) {
    int f = threadIdx.x;
    int n0 = blockIdx.x * POOL_CHUNK;
    if (n0 >= N) return;
    int n1 = n0 + POOL_CHUNK; if (n1 > N) n1 = N;
    int g = batch[n0];
    float m = 0.f;
    for (int n = n0; n < n1; ++n) {
        int bg = batch[n];
        if (bg != g) {
            atomicMax(&pooled[g * 128 + f], __float_as_uint(m));
            m = 0.f; g = bg;
        }
        m = fmaxf(m, (float)x16[(size_t)n * 128 + f]);
    }
    atomicMax(&pooled[g * 128 + f], __float_as_uint(m));
}

// ---------------- head ----------------

__global__ __launch_bounds__(256) void head_kernel(
    const float* __restrict__ pooled,
    const float* __restrict__ linW, const float* __restrict__ linb,
    const float* __restrict__ outW, const float* __restrict__ outb,
    float* __restrict__ out)
{
    __shared__ float pl[128];
    __shared__ float hrow[256];
    int g = blockIdx.x, t = threadIdx.x;
    if (t < 128) pl[t] = pooled[g * 128 + t];
    __syncthreads();
    float acc = linb[t];
    for (int k = 0; k < 128; ++k) acc += pl[k] * linW[k * 256 + t];
    hrow[t] = acc;
    __syncthreads();
    if (t < 10) {
        float o = outb[t];
        for (int k = 0; k < 256; ++k) o += hrow[k] * outW[k * 10 + t];
        out[g * 10 + t] = o;
    }
}

// ---------------- launch ----------------

static inline size_t align_up(size_t v, size_t a) { return (v + a - 1) & ~(a - 1); }

extern "C" void kernel_launch(void* const* d_in, const int* in_sizes, int n_in,
                              void* d_out, int out_size, void* d_ws, size_t ws_size,
                              hipStream_t stream) {
    const float* x      = (const float*)d_in[0];
    const int*   ei     = (const int*)d_in[1];
    const int*   batch  = (const int*)d_in[2];
    const float* WsSelf = (const float*)d_in[3];
    const float* WsNei  = (const float*)d_in[4];
    const float* bsAll  = (const float*)d_in[5];
    const float* linW   = (const float*)d_in[6];
    const float* linb   = (const float*)d_in[7];
    const float* outW   = (const float*)d_in[8];
    const float* outb   = (const float*)d_in[9];

    const int N = in_sizes[0] / 128;
    const int E = in_sizes[1] / 2;
    const int L = in_sizes[3] / (128 * 128);
    const int* src = ei;
    const int* dst = ei + E;

    // workspace carve (~55 MB)
    char* w = (char*)d_ws;
    int* cnt       = (int*)w;  w += align_up((size_t)N * 4, 256);
    int* row_start = (int*)w;  w += align_up((size_t)N * 4, 256);
    int* cursor    = (int*)w;  w += align_up((size_t)N * 4, 256);
    int* bsum      = (int*)w;  w += align_up(256 * 4, 256);
    int* boff      = (int*)w;  w += align_up(256 * 4, 256);
    int* col       = (int*)w;  w += align_up((size_t)E * 4, 256);
    _Float16* agg16 = (_Float16*)w; w += align_up((size_t)N * 128 * 2, 256);
    _Float16* x16in = (_Float16*)w; w += align_up((size_t)N * 128 * 2, 256);
    _Float16* xa16  = (_Float16*)w; w += align_up((size_t)N * 128 * 2, 256);
    _Float16* xb16  = (_Float16*)w; w += align_up((size_t)N * 128 * 2, 256);
    float* pooled  = (float*)w; w += align_up((size_t)64 * 128 * 4, 256);
    unsigned short* Wfh = (unsigned short*)w; w += align_up((size_t)L * 2 * 16384 * 2, 256);
    unsigned short* Wfl = (unsigned short*)w; w += align_up((size_t)L * 2 * 16384 * 2, 256);
    (void)ws_size;

    hipMemsetAsync(cnt, 0, (size_t)N * 4, stream);
    hipMemsetAsync(pooled, 0, (size_t)64 * 128 * 4, stream);

    cvt16_kernel<<<(N * 16 + 255) / 256, 256, 0, stream>>>(x, x16in, N * 16);

    const int wtotal = L * 2 * 128 * 128;
    wprep_kernel<<<(wtotal + 255) / 256, 256, 0, stream>>>(WsNei, WsSelf, wtotal, Wfh, Wfl);

    const int nb = (N + 255) / 256;   // 196 <= 256
    hist_kernel<<<(E + 255) / 256, 256, 0, stream>>>(dst, E, cnt);
    bsum_kernel<<<nb, 256, 0, stream>>>(cnt, N, bsum);
    bscan_kernel<<<1, 256, 0, stream>>>(bsum, nb, boff);
    scan_apply_kernel<<<nb, 256, 0, stream>>>(cnt, N, boff, row_start, cursor);
    fill_kernel<<<(E + 255) / 256, 256, 0, stream>>>(src, dst, E, cursor, col);

    const _Float16* xin16 = x16in;
    _Float16* bufs[2] = { xa16, xb16 };
    for (int l = 0; l < L; ++l) {
        agg_kernel<<<(N * 32 + 255) / 256, 256, 0, stream>>>(xin16, row_start, cnt, col, agg16, N);
        layer_mfma<<<(N + 127) / 128, 256, 0, stream>>>(
            agg16, xin16,
            Wfh + (size_t)l * 2 * 16384, Wfl + (size_t)l * 2 * 16384,
            bsAll + (size_t)l * 128, bufs[l & 1], N);
        xin16 = bufs[l & 1];
    }

    pool_kernel<<<(N + POOL_CHUNK - 1) / POOL_CHUNK, 128, 0, stream>>>(
        xin16, batch, N, (unsigned int*)pooled);
    head_kernel<<<64, 256, 0, stream>>>(pooled, linW, linb, outW, outb, (float*)d_out);
}

// Round 5
// 409.244 us; speedup vs baseline: 2.3183x; 1.1565x over previous
//
#include <hip/hip_runtime.h>
#include <float.h>

typedef __bf16 bf16x8 __attribute__((ext_vector_type(8)));
typedef float f32x4 __attribute__((ext_vector_type(4)));
typedef unsigned short ushort8 __attribute__((ext_vector_type(8)));
typedef _Float16 h8 __attribute__((ext_vector_type(8)));
typedef _Float16 h4 __attribute__((ext_vector_type(4)));

__device__ inline unsigned short f2bh(float f) {
    unsigned int u = __float_as_uint(f);
    return (unsigned short)((u + 0x7FFFu + ((u >> 16) & 1u)) >> 16);
}
__device__ inline float bh2f(unsigned short h) {
    return __uint_as_float((unsigned int)h << 16);
}

// ---------------- fp32 -> fp16 convert (input x once per launch) ----------------

__global__ void cvt16_kernel(const float* __restrict__ xin, _Float16* __restrict__ x16,
                             int total8) {
    int i = blockIdx.x * blockDim.x + threadIdx.x;
    if (i >= total8) return;
    const float4* p = reinterpret_cast<const float4*>(xin + (size_t)i * 8);
    float4 a = p[0], b = p[1];
    h8 o;
    o[0] = (_Float16)a.x; o[1] = (_Float16)a.y; o[2] = (_Float16)a.z; o[3] = (_Float16)a.w;
    o[4] = (_Float16)b.x; o[5] = (_Float16)b.y; o[6] = (_Float16)b.z; o[7] = (_Float16)b.w;
    *reinterpret_cast<h8*>(x16 + (size_t)i * 8) = o;
}

// ---------------- CSR build (by dst): hist + 3-phase parallel scan + fill ----------------

__global__ void hist_kernel(const int* __restrict__ dst, int E, int* __restrict__ cnt) {
    int e = blockIdx.x * blockDim.x + threadIdx.x;
    if (e < E) atomicAdd(&cnt[dst[e]], 1);
}

__global__ __launch_bounds__(256) void bsum_kernel(const int* __restrict__ cnt, int N,
                                                   int* __restrict__ bsum) {
    __shared__ int red[256];
    int t = threadIdx.x;
    int i = blockIdx.x * 256 + t;
    red[t] = (i < N) ? cnt[i] : 0;
    __syncthreads();
    for (int off = 128; off > 0; off >>= 1) {
        if (t < off) red[t] += red[t + off];
        __syncthreads();
    }
    if (t == 0) bsum[blockIdx.x] = red[0];
}

__global__ __launch_bounds__(256) void bscan_kernel(const int* __restrict__ bsum, int nb,
                                                    int* __restrict__ boff) {
    __shared__ int s[256];
    int t = threadIdx.x;
    int v = (t < nb) ? bsum[t] : 0;
    s[t] = v;
    __syncthreads();
    for (int off = 1; off < 256; off <<= 1) {
        int u = (t >= off) ? s[t - off] : 0;
        __syncthreads();
        s[t] += u;
        __syncthreads();
    }
    if (t < nb) boff[t] = s[t] - v;   // exclusive block offset
}

__global__ __launch_bounds__(256) void scan_apply_kernel(const int* __restrict__ cnt, int N,
                                                         const int* __restrict__ boff,
                                                         int* __restrict__ row_start,
                                                         int* __restrict__ cursor) {
    __shared__ int s[256];
    int t = threadIdx.x;
    int i = blockIdx.x * 256 + t;
    int v = (i < N) ? cnt[i] : 0;
    s[t] = v;
    __syncthreads();
    for (int off = 1; off < 256; off <<= 1) {
        int u = (t >= off) ? s[t - off] : 0;
        __syncthreads();
        s[t] += u;
        __syncthreads();
    }
    int excl = boff[blockIdx.x] + s[t] - v;
    if (i < N) { row_start[i] = excl; cursor[i] = excl; }
}

__global__ void fill_kernel(const int* __restrict__ src, const int* __restrict__ dst, int E,
                            int* __restrict__ cursor, int* __restrict__ col) {
    int e = blockIdx.x * blockDim.x + threadIdx.x;
    if (e < E) {
        int d = dst[e];
        int pos = atomicAdd(&cursor[d], 1);
        col[pos] = src[e];
    }
}

// ---------------- max aggregation (fp16): 32 lanes/node, 4 halves/lane ----------------

__global__ void agg_kernel(const _Float16* __restrict__ x16,
                           const int* __restrict__ row_start, const int* __restrict__ cnt,
                           const int* __restrict__ col,
                           _Float16* __restrict__ agg16, int N) {
    int node = (blockIdx.x * blockDim.x + threadIdx.x) >> 5;
    int lane = threadIdx.x & 31;
    if (node >= N) return;
    int beg = row_start[node];
    int deg = cnt[node];
    const _Float16 NEG = (_Float16)(-65504.0f);
    _Float16 m0 = NEG, m1 = NEG, m2 = NEG, m3 = NEG;
    for (int j = 0; j < deg; ++j) {
        int s = col[beg + j];
        h4 v = *reinterpret_cast<const h4*>(&x16[(size_t)s * 128 + lane * 4]);
        m0 = v[0] > m0 ? v[0] : m0;
        m1 = v[1] > m1 ? v[1] : m1;
        m2 = v[2] > m2 ? v[2] : m2;
        m3 = v[3] > m3 ? v[3] : m3;
    }
    if (deg == 0) { m0 = (_Float16)0.f; m1 = (_Float16)0.f; m2 = (_Float16)0.f; m3 = (_Float16)0.f; }
    h4 o; o[0] = m0; o[1] = m1; o[2] = m2; o[3] = m3;
    *reinterpret_cast<h4*>(&agg16[(size_t)node * 128 + lane * 4]) = o;
}

// ---------------- W prep: split fp32 W into bf16 hi/lo, fragment-ordered ----------------
// dest layout per layer: [phase(2)][kgroup(16)][col(128)][j(8)]; phase0=Wnei, phase1=Wself.

__global__ void wprep_kernel(const float* __restrict__ Wn, const float* __restrict__ Wsf,
                             int total, unsigned short* __restrict__ Wfh,
                             unsigned short* __restrict__ Wfl) {
    int idx = blockIdx.x * blockDim.x + threadIdx.x;
    if (idx >= total) return;
    int c = idx & 127;
    int k = (idx >> 7) & 127;
    int p = (idx >> 14) & 1;
    int l = idx >> 15;
    const float* W = p ? Wsf : Wn;
    float v = W[(size_t)l * 16384 + k * 128 + c];
    unsigned short hi = f2bh(v);
    unsigned short lo = f2bh(v - bh2f(hi));
    size_t d = ((((size_t)l * 2 + p) * 16 + (k >> 3)) * 128 + c) * 8 + (k & 7);
    Wfh[d] = hi;
    Wfl[d] = lo;
}

// ---------------- fused layer GEMM via MFMA: relu([agg|x]@[Wn;Ws] + b) ----------------
// 16 rows x 64 cols per wave -> 6250 waves (~6.1/SIMD supply) for latency hiding.
// 3-term split-bf16 (Ah@Wh + Al@Wh + Ah@Wl); fp16 A splits exactly into bf16 hi+lo.

__global__ __launch_bounds__(256) void layer_mfma(
    const _Float16* __restrict__ agg16, const _Float16* __restrict__ xin16,
    const unsigned short* __restrict__ Wfh, const unsigned short* __restrict__ Wfl,
    const float* __restrict__ bias, _Float16* __restrict__ xout16, int N)
{
    const int lane = threadIdx.x & 63;
    const int wid  = threadIdx.x >> 6;   // 0..3
    const int l15  = lane & 15;
    const int lg   = lane >> 4;          // 0..3
    const int ch   = wid & 1;            // col half: cols ch*64 .. ch*64+63
    const int rg   = wid >> 1;           // row group within block
    const int row0 = blockIdx.x * 32 + rg * 16;

    f32x4 acc[4];
    #pragma unroll
    for (int nt = 0; nt < 4; ++nt) { f32x4 z = {0.f,0.f,0.f,0.f}; acc[nt] = z; }

    int rc = row0 + l15; if (rc > N - 1) rc = N - 1;

    #pragma unroll
    for (int p = 0; p < 2; ++p) {
        const _Float16* A = p ? xin16 : agg16;
        const _Float16* a = A + (size_t)rc * 128 + lg * 8;
        const unsigned short* wh0 = Wfh + p * 16384 + (size_t)(ch * 64 + l15) * 8 + lg * 1024;
        const unsigned short* wl0 = Wfl + p * 16384 + (size_t)(ch * 64 + l15) * 8 + lg * 1024;
        #pragma unroll
        for (int ks = 0; ks < 4; ++ks) {
            h8 av = *reinterpret_cast<const h8*>(a + ks * 32);
            ushort8 hh, ll;
            #pragma unroll
            for (int j = 0; j < 8; ++j) {
                float f = (float)av[j];
                unsigned short hi = f2bh(f);
                float r = f - bh2f(hi);          // exactly representable in bf16
                hh[j] = hi;
                ll[j] = (unsigned short)(__float_as_uint(r) >> 16);
            }
            bf16x8 ah = __builtin_bit_cast(bf16x8, hh);
            bf16x8 al = __builtin_bit_cast(bf16x8, ll);
            const unsigned short* whk = wh0 + ks * 4096;  // kgroup = ks*4 + lg
            const unsigned short* wlk = wl0 + ks * 4096;
            #pragma unroll
            for (int nt = 0; nt < 4; ++nt) {
                bf16x8 bh = *reinterpret_cast<const bf16x8*>(whk + nt * 128);
                bf16x8 bl = *reinterpret_cast<const bf16x8*>(wlk + nt * 128);
                acc[nt] = __builtin_amdgcn_mfma_f32_16x16x32_bf16(ah, bh, acc[nt], 0, 0, 0);
                acc[nt] = __builtin_amdgcn_mfma_f32_16x16x32_bf16(al, bh, acc[nt], 0, 0, 0);
                acc[nt] = __builtin_amdgcn_mfma_f32_16x16x32_bf16(ah, bl, acc[nt], 0, 0, 0);
            }
        }
    }

    #pragma unroll
    for (int nt = 0; nt < 4; ++nt) {
        int colb = ch * 64 + nt * 16 + l15;
        float bv = bias[colb];
        #pragma unroll
        for (int rr = 0; rr < 4; ++rr) {
            int row = row0 + lg * 4 + rr;
            if (row < N) {
                float o = fmaxf(acc[nt][rr] + bv, 0.f);
                xout16[(size_t)row * 128 + colb] = (_Float16)o;
            }
        }
    }
}

// ---------------- global max pool per graph: chunked + atomicMax ----------------

#define POOL_CHUNK 128

__global__ __launch_bounds__(128) void pool_kernel(const _Float16* __restrict__ x16,
                                                   const int* __restrict__ batch,
                                                   int N,
                                                   unsigned int* __restrict__ pooled) {
    int f = threadIdx.x;
    int n0 = blockIdx.x * POOL_CHUNK;
    if (n0 >= N) return;
    int n1 = n0 + POOL_CHUNK; if (n1 > N) n1 = N;
    int g = batch[n0];
    float m = 0.f;
    for (int n = n0; n < n1; ++n) {
        int bg = batch[n];
        if (bg != g) {
            atomicMax(&pooled[g * 128 + f], __float_as_uint(m));
            m = 0.f; g = bg;
        }
        m = fmaxf(m, (float)x16[(size_t)n * 128 + f]);
    }
    atomicMax(&pooled[g * 128 + f], __float_as_uint(m));
}

// ---------------- head ----------------

__global__ __launch_bounds__(256) void head_kernel(
    const float* __restrict__ pooled,
    const float* __restrict__ linW, const float* __restrict__ linb,
    const float* __restrict__ outW, const float* __restrict__ outb,
    float* __restrict__ out)
{
    __shared__ float pl[128];
    __shared__ float hrow[256];
    int g = blockIdx.x, t = threadIdx.x;
    if (t < 128) pl[t] = pooled[g * 128 + t];
    __syncthreads();
    float acc = linb[t];
    for (int k = 0; k < 128; ++k) acc += pl[k] * linW[k * 256 + t];
    hrow[t] = acc;
    __syncthreads();
    if (t < 10) {
        float o = outb[t];
        for (int k = 0; k < 256; ++k) o += hrow[k] * outW[k * 10 + t];
        out[g * 10 + t] = o;
    }
}

// ---------------- launch ----------------

static inline size_t align_up(size_t v, size_t a) { return (v + a - 1) & ~(a - 1); }

extern "C" void kernel_launch(void* const* d_in, const int* in_sizes, int n_in,
                              void* d_out, int out_size, void* d_ws, size_t ws_size,
                              hipStream_t stream) {
    const float* x      = (const float*)d_in[0];
    const int*   ei     = (const int*)d_in[1];
    const int*   batch  = (const int*)d_in[2];
    const float* WsSelf = (const float*)d_in[3];
    const float* WsNei  = (const float*)d_in[4];
    const float* bsAll  = (const float*)d_in[5];
    const float* linW   = (const float*)d_in[6];
    const float* linb   = (const float*)d_in[7];
    const float* outW   = (const float*)d_in[8];
    const float* outb   = (const float*)d_in[9];

    const int N = in_sizes[0] / 128;
    const int E = in_sizes[1] / 2;
    const int L = in_sizes[3] / (128 * 128);
    const int* src = ei;
    const int* dst = ei + E;

    // workspace carve (~55 MB)
    char* w = (char*)d_ws;
    int* cnt       = (int*)w;  w += align_up((size_t)N * 4, 256);
    int* row_start = (int*)w;  w += align_up((size_t)N * 4, 256);
    int* cursor    = (int*)w;  w += align_up((size_t)N * 4, 256);
    int* bsum      = (int*)w;  w += align_up(256 * 4, 256);
    int* boff      = (int*)w;  w += align_up(256 * 4, 256);
    int* col       = (int*)w;  w += align_up((size_t)E * 4, 256);
    _Float16* agg16 = (_Float16*)w; w += align_up((size_t)N * 128 * 2, 256);
    _Float16* x16in = (_Float16*)w; w += align_up((size_t)N * 128 * 2, 256);
    _Float16* xa16  = (_Float16*)w; w += align_up((size_t)N * 128 * 2, 256);
    _Float16* xb16  = (_Float16*)w; w += align_up((size_t)N * 128 * 2, 256);
    float* pooled  = (float*)w; w += align_up((size_t)64 * 128 * 4, 256);
    unsigned short* Wfh = (unsigned short*)w; w += align_up((size_t)L * 2 * 16384 * 2, 256);
    unsigned short* Wfl = (unsigned short*)w; w += align_up((size_t)L * 2 * 16384 * 2, 256);
    (void)ws_size;

    hipMemsetAsync(cnt, 0, (size_t)N * 4, stream);
    hipMemsetAsync(pooled, 0, (size_t)64 * 128 * 4, stream);

    cvt16_kernel<<<(N * 16 + 255) / 256, 256, 0, stream>>>(x, x16in, N * 16);

    const int wtotal = L * 2 * 128 * 128;
    wprep_kernel<<<(wtotal + 255) / 256, 256, 0, stream>>>(WsNei, WsSelf, wtotal, Wfh, Wfl);

    const int nb = (N + 255) / 256;
    hist_kernel<<<(E + 255) / 256, 256, 0, stream>>>(dst, E, cnt);
    bsum_kernel<<<nb, 256, 0, stream>>>(cnt, N, bsum);
    bscan_kernel<<<1, 256, 0, stream>>>(bsum, nb, boff);
    scan_apply_kernel<<<nb, 256, 0, stream>>>(cnt, N, boff, row_start, cursor);
    fill_kernel<<<(E + 255) / 256, 256, 0, stream>>>(src, dst, E, cursor, col);

    const _Float16* xin16 = x16in;
    _Float16* bufs[2] = { xa16, xb16 };
    for (int l = 0; l < L; ++l) {
        agg_kernel<<<(N * 32 + 255) / 256, 256, 0, stream>>>(xin16, row_start, cnt, col, agg16, N);
        layer_mfma<<<(N + 31) / 32, 256, 0, stream>>>(
            agg16, xin16,
            Wfh + (size_t)l * 2 * 16384, Wfl + (size_t)l * 2 * 16384,
            bsAll + (size_t)l * 128, bufs[l & 1], N);
        xin16 = bufs[l & 1];
    }

    pool_kernel<<<(N + POOL_CHUNK - 1) / POOL_CHUNK, 128, 0, stream>>>(
        xin16, batch, N, (unsigned int*)pooled);
    head_kernel<<<64, 256, 0, stream>>>(pooled, linW, linb, outW, outb, (float*)d_out);
}

// Round 6
// 336.480 us; speedup vs baseline: 2.8196x; 1.2163x over previous
//
#include <hip/hip_runtime.h>
#include <float.h>

typedef __bf16 bf16x8 __attribute__((ext_vector_type(8)));
typedef float f32x4 __attribute__((ext_vector_type(4)));
typedef unsigned short ushort8 __attribute__((ext_vector_type(8)));
typedef _Float16 h8 __attribute__((ext_vector_type(8)));
typedef _Float16 h4 __attribute__((ext_vector_type(4)));

__device__ inline unsigned short f2bh(float f) {
    unsigned int u = __float_as_uint(f);
    return (unsigned short)((u + 0x7FFFu + ((u >> 16) & 1u)) >> 16);
}
__device__ inline float bh2f(unsigned short h) {
    return __uint_as_float((unsigned int)h << 16);
}
__device__ inline h4 h4max(h4 a, h4 b) {
    h4 r;
    r[0] = a[0] > b[0] ? a[0] : b[0];
    r[1] = a[1] > b[1] ? a[1] : b[1];
    r[2] = a[2] > b[2] ? a[2] : b[2];
    r[3] = a[3] > b[3] ? a[3] : b[3];
    return r;
}

// ---------------- fp32 -> fp16 convert (input x once per launch) ----------------

__global__ void cvt16_kernel(const float* __restrict__ xin, _Float16* __restrict__ x16,
                             int total8) {
    int i = blockIdx.x * blockDim.x + threadIdx.x;
    if (i >= total8) return;
    const float4* p = reinterpret_cast<const float4*>(xin + (size_t)i * 8);
    float4 a = p[0], b = p[1];
    h8 o;
    o[0] = (_Float16)a.x; o[1] = (_Float16)a.y; o[2] = (_Float16)a.z; o[3] = (_Float16)a.w;
    o[4] = (_Float16)b.x; o[5] = (_Float16)b.y; o[6] = (_Float16)b.z; o[7] = (_Float16)b.w;
    *reinterpret_cast<h8*>(x16 + (size_t)i * 8) = o;
}

// ---------------- CSR build (by dst): hist + 2-phase parallel scan + fill ----------------

__global__ void hist_kernel(const int* __restrict__ dst, int E, int* __restrict__ cnt) {
    int e = blockIdx.x * blockDim.x + threadIdx.x;
    if (e < E) atomicAdd(&cnt[dst[e]], 1);
}

__global__ __launch_bounds__(256) void bsum_kernel(const int* __restrict__ cnt, int N,
                                                   int* __restrict__ bsum) {
    __shared__ int red[256];
    int t = threadIdx.x;
    int i = blockIdx.x * 256 + t;
    red[t] = (i < N) ? cnt[i] : 0;
    __syncthreads();
    for (int off = 128; off > 0; off >>= 1) {
        if (t < off) red[t] += red[t + off];
        __syncthreads();
    }
    if (t == 0) bsum[blockIdx.x] = red[0];
}

// Each block redundantly scans the (<=256) block sums, then scans its own 256
// counts and writes row_start/cursor. Merges the old bscan+scan_apply pair.
__global__ __launch_bounds__(256) void scan_apply_kernel(const int* __restrict__ cnt, int N,
                                                         const int* __restrict__ bsum, int nb,
                                                         int* __restrict__ row_start,
                                                         int* __restrict__ cursor) {
    __shared__ int sb[256];
    __shared__ int s[256];
    int t = threadIdx.x;
    sb[t] = (t < nb) ? bsum[t] : 0;
    int i = blockIdx.x * 256 + t;
    int v = (i < N) ? cnt[i] : 0;
    s[t] = v;
    __syncthreads();
    for (int off = 1; off < 256; off <<= 1) {
        int u0 = (t >= off) ? sb[t - off] : 0;
        int u1 = (t >= off) ? s[t - off] : 0;
        __syncthreads();
        sb[t] += u0;
        s[t] += u1;
        __syncthreads();
    }
    int base = (blockIdx.x == 0) ? 0 : sb[blockIdx.x - 1];
    int excl = base + s[t] - v;
    if (i < N) { row_start[i] = excl; cursor[i] = excl; }
}

__global__ void fill_kernel(const int* __restrict__ src, const int* __restrict__ dst, int E,
                            int* __restrict__ cursor, int* __restrict__ col) {
    int e = blockIdx.x * blockDim.x + threadIdx.x;
    if (e < E) {
        int d = dst[e];
        int pos = atomicAdd(&cursor[d], 1);
        col[pos] = src[e];
    }
}

// ---------------- max aggregation (fp16): 32 lanes/node, 4-way unrolled gather ----------------
// 4 independent col-loads + 4 independent row gathers + 4 independent max
// accumulators per iteration -> breaks the col->gather->fmax latency chain.

__global__ void agg_kernel(const _Float16* __restrict__ x16,
                           const int* __restrict__ row_start, const int* __restrict__ cnt,
                           const int* __restrict__ col,
                           _Float16* __restrict__ agg16, int N) {
    int node = (blockIdx.x * blockDim.x + threadIdx.x) >> 5;
    int lane = threadIdx.x & 31;
    if (node >= N) return;
    int beg = row_start[node];
    int deg = cnt[node];
    const _Float16 NEG = (_Float16)(-65504.0f);
    h4 a0, a1, a2, a3;
    a0[0]=NEG; a0[1]=NEG; a0[2]=NEG; a0[3]=NEG;
    a1 = a0; a2 = a0; a3 = a0;
    int j = 0;
    for (; j + 4 <= deg; j += 4) {
        int s0 = col[beg + j];
        int s1 = col[beg + j + 1];
        int s2 = col[beg + j + 2];
        int s3 = col[beg + j + 3];
        h4 v0 = *reinterpret_cast<const h4*>(&x16[(size_t)s0 * 128 + lane * 4]);
        h4 v1 = *reinterpret_cast<const h4*>(&x16[(size_t)s1 * 128 + lane * 4]);
        h4 v2 = *reinterpret_cast<const h4*>(&x16[(size_t)s2 * 128 + lane * 4]);
        h4 v3 = *reinterpret_cast<const h4*>(&x16[(size_t)s3 * 128 + lane * 4]);
        a0 = h4max(a0, v0);
        a1 = h4max(a1, v1);
        a2 = h4max(a2, v2);
        a3 = h4max(a3, v3);
    }
    for (; j < deg; ++j) {
        int s0 = col[beg + j];
        h4 v0 = *reinterpret_cast<const h4*>(&x16[(size_t)s0 * 128 + lane * 4]);
        a0 = h4max(a0, v0);
    }
    a0 = h4max(h4max(a0, a1), h4max(a2, a3));
    if (deg == 0) { a0[0] = (_Float16)0.f; a0[1] = (_Float16)0.f; a0[2] = (_Float16)0.f; a0[3] = (_Float16)0.f; }
    *reinterpret_cast<h4*>(&agg16[(size_t)node * 128 + lane * 4]) = a0;
}

// ---------------- W prep: split fp32 W into bf16 hi/lo, fragment-ordered ----------------
// dest layout per layer: [phase(2)][kgroup(16)][col(128)][j(8)]; phase0=Wnei, phase1=Wself.

__global__ void wprep_kernel(const float* __restrict__ Wn, const float* __restrict__ Wsf,
                             int total, unsigned short* __restrict__ Wfh,
                             unsigned short* __restrict__ Wfl) {
    int idx = blockIdx.x * blockDim.x + threadIdx.x;
    if (idx >= total) return;
    int c = idx & 127;
    int k = (idx >> 7) & 127;
    int p = (idx >> 14) & 1;
    int l = idx >> 15;
    const float* W = p ? Wsf : Wn;
    float v = W[(size_t)l * 16384 + k * 128 + c];
    unsigned short hi = f2bh(v);
    unsigned short lo = f2bh(v - bh2f(hi));
    size_t d = ((((size_t)l * 2 + p) * 16 + (k >> 3)) * 128 + c) * 8 + (k & 7);
    Wfh[d] = hi;
    Wfl[d] = lo;
}

// ---------------- fused layer GEMM via MFMA: relu([agg|x]@[Wn;Ws] + b) ----------------
// 16 rows x 64 cols per wave -> 6250 waves (~6.1/SIMD supply) for latency hiding.
// 3-term split-bf16 (Ah@Wh + Al@Wh + Ah@Wl); fp16 A splits exactly into bf16 hi+lo.

__global__ __launch_bounds__(256) void layer_mfma(
    const _Float16* __restrict__ agg16, const _Float16* __restrict__ xin16,
    const unsigned short* __restrict__ Wfh, const unsigned short* __restrict__ Wfl,
    const float* __restrict__ bias, _Float16* __restrict__ xout16, int N)
{
    const int lane = threadIdx.x & 63;
    const int wid  = threadIdx.x >> 6;   // 0..3
    const int l15  = lane & 15;
    const int lg   = lane >> 4;          // 0..3
    const int ch   = wid & 1;            // col half: cols ch*64 .. ch*64+63
    const int rg   = wid >> 1;           // row group within block
    const int row0 = blockIdx.x * 32 + rg * 16;

    f32x4 acc[4];
    #pragma unroll
    for (int nt = 0; nt < 4; ++nt) { f32x4 z = {0.f,0.f,0.f,0.f}; acc[nt] = z; }

    int rc = row0 + l15; if (rc > N - 1) rc = N - 1;

    #pragma unroll
    for (int p = 0; p < 2; ++p) {
        const _Float16* A = p ? xin16 : agg16;
        const _Float16* a = A + (size_t)rc * 128 + lg * 8;
        const unsigned short* wh0 = Wfh + p * 16384 + (size_t)(ch * 64 + l15) * 8 + lg * 1024;
        const unsigned short* wl0 = Wfl + p * 16384 + (size_t)(ch * 64 + l15) * 8 + lg * 1024;
        #pragma unroll
        for (int ks = 0; ks < 4; ++ks) {
            h8 av = *reinterpret_cast<const h8*>(a + ks * 32);
            ushort8 hh, ll;
            #pragma unroll
            for (int j = 0; j < 8; ++j) {
                float f = (float)av[j];
                unsigned short hi = f2bh(f);
                float r = f - bh2f(hi);          // exactly representable in bf16
                hh[j] = hi;
                ll[j] = (unsigned short)(__float_as_uint(r) >> 16);
            }
            bf16x8 ah = __builtin_bit_cast(bf16x8, hh);
            bf16x8 al = __builtin_bit_cast(bf16x8, ll);
            const unsigned short* whk = wh0 + ks * 4096;  // kgroup = ks*4 + lg
            const unsigned short* wlk = wl0 + ks * 4096;
            #pragma unroll
            for (int nt = 0; nt < 4; ++nt) {
                bf16x8 bh = *reinterpret_cast<const bf16x8*>(whk + nt * 128);
                bf16x8 bl = *reinterpret_cast<const bf16x8*>(wlk + nt * 128);
                acc[nt] = __builtin_amdgcn_mfma_f32_16x16x32_bf16(ah, bh, acc[nt], 0, 0, 0);
                acc[nt] = __builtin_amdgcn_mfma_f32_16x16x32_bf16(al, bh, acc[nt], 0, 0, 0);
                acc[nt] = __builtin_amdgcn_mfma_f32_16x16x32_bf16(ah, bl, acc[nt], 0, 0, 0);
            }
        }
    }

    #pragma unroll
    for (int nt = 0; nt < 4; ++nt) {
        int colb = ch * 64 + nt * 16 + l15;
        float bv = bias[colb];
        #pragma unroll
        for (int rr = 0; rr < 4; ++rr) {
            int row = row0 + lg * 4 + rr;
            if (row < N) {
                float o = fmaxf(acc[nt][rr] + bv, 0.f);
                xout16[(size_t)row * 128 + colb] = (_Float16)o;
            }
        }
    }
}

// ---------------- global max pool per graph: chunked + atomicMax ----------------

#define POOL_CHUNK 128

__global__ __launch_bounds__(128) void pool_kernel(const _Float16* __restrict__ x16,
                                                   const int* __restrict__ batch,
                                                   int N,
                                                   unsigned int* __restrict__ pooled) {
    int f = threadIdx.x;
    int n0 = blockIdx.x * POOL_CHUNK;
    if (n0 >= N) return;
    int n1 = n0 + POOL_CHUNK; if (n1 > N) n1 = N;
    int g = batch[n0];
    float m = 0.f;
    for (int n = n0; n < n1; ++n) {
        int bg = batch[n];
        if (bg != g) {
            atomicMax(&pooled[g * 128 + f], __float_as_uint(m));
            m = 0.f; g = bg;
        }
        m = fmaxf(m, (float)x16[(size_t)n * 128 + f]);
    }
    atomicMax(&pooled[g * 128 + f], __float_as_uint(m));
}

// ---------------- head ----------------

__global__ __launch_bounds__(256) void head_kernel(
    const float* __restrict__ pooled,
    const float* __restrict__ linW, const float* __restrict__ linb,
    const float* __restrict__ outW, const float* __restrict__ outb,
    float* __restrict__ out)
{
    __shared__ float pl[128];
    __shared__ float hrow[256];
    int g = blockIdx.x, t = threadIdx.x;
    if (t < 128) pl[t] = pooled[g * 128 + t];
    __syncthreads();
    float acc = linb[t];
    for (int k = 0; k < 128; ++k) acc += pl[k] * linW[k * 256 + t];
    hrow[t] = acc;
    __syncthreads();
    if (t < 10) {
        float o = outb[t];
        for (int k = 0; k < 256; ++k) o += hrow[k] * outW[k * 10 + t];
        out[g * 10 + t] = o;
    }
}

// ---------------- launch ----------------

static inline size_t align_up(size_t v, size_t a) { return (v + a - 1) & ~(a - 1); }

extern "C" void kernel_launch(void* const* d_in, const int* in_sizes, int n_in,
                              void* d_out, int out_size, void* d_ws, size_t ws_size,
                              hipStream_t stream) {
    const float* x      = (const float*)d_in[0];
    const int*   ei     = (const int*)d_in[1];
    const int*   batch  = (const int*)d_in[2];
    const float* WsSelf = (const float*)d_in[3];
    const float* WsNei  = (const float*)d_in[4];
    const float* bsAll  = (const float*)d_in[5];
    const float* linW   = (const float*)d_in[6];
    const float* linb   = (const float*)d_in[7];
    const float* outW   = (const float*)d_in[8];
    const float* outb   = (const float*)d_in[9];

    const int N = in_sizes[0] / 128;
    const int E = in_sizes[1] / 2;
    const int L = in_sizes[3] / (128 * 128);
    const int* src = ei;
    const int* dst = ei + E;

    // workspace carve (~55 MB)
    char* w = (char*)d_ws;
    int* cnt       = (int*)w;  w += align_up((size_t)N * 4, 256);
    int* row_start = (int*)w;  w += align_up((size_t)N * 4, 256);
    int* cursor    = (int*)w;  w += align_up((size_t)N * 4, 256);
    int* bsum      = (int*)w;  w += align_up(256 * 4, 256);
    int* col       = (int*)w;  w += align_up((size_t)E * 4, 256);
    _Float16* agg16 = (_Float16*)w; w += align_up((size_t)N * 128 * 2, 256);
    _Float16* x16in = (_Float16*)w; w += align_up((size_t)N * 128 * 2, 256);
    _Float16* xa16  = (_Float16*)w; w += align_up((size_t)N * 128 * 2, 256);
    _Float16* xb16  = (_Float16*)w; w += align_up((size_t)N * 128 * 2, 256);
    float* pooled  = (float*)w; w += align_up((size_t)64 * 128 * 4, 256);
    unsigned short* Wfh = (unsigned short*)w; w += align_up((size_t)L * 2 * 16384 * 2, 256);
    unsigned short* Wfl = (unsigned short*)w; w += align_up((size_t)L * 2 * 16384 * 2, 256);
    (void)ws_size;

    hipMemsetAsync(cnt, 0, (size_t)N * 4, stream);
    hipMemsetAsync(pooled, 0, (size_t)64 * 128 * 4, stream);

    cvt16_kernel<<<(N * 16 + 255) / 256, 256, 0, stream>>>(x, x16in, N * 16);

    const int wtotal = L * 2 * 128 * 128;
    wprep_kernel<<<(wtotal + 255) / 256, 256, 0, stream>>>(WsNei, WsSelf, wtotal, Wfh, Wfl);

    const int nb = (N + 255) / 256;
    hist_kernel<<<(E + 255) / 256, 256, 0, stream>>>(dst, E, cnt);
    bsum_kernel<<<nb, 256, 0, stream>>>(cnt, N, bsum);
    scan_apply_kernel<<<nb, 256, 0, stream>>>(cnt, N, bsum, nb, row_start, cursor);
    fill_kernel<<<(E + 255) / 256, 256, 0, stream>>>(src, dst, E, cursor, col);

    const _Float16* xin16 = x16in;
    _Float16* bufs[2] = { xa16, xb16 };
    for (int l = 0; l < L; ++l) {
        agg_kernel<<<(N * 32 + 255) / 256, 256, 0, stream>>>(xin16, row_start, cnt, col, agg16, N);
        layer_mfma<<<(N + 31) / 32, 256, 0, stream>>>(
            agg16, xin16,
            Wfh + (size_t)l * 2 * 16384, Wfl + (size_t)l * 2 * 16384,
            bsAll + (size_t)l * 128, bufs[l & 1], N);
        xin16 = bufs[l & 1];
    }

    pool_kernel<<<(N + POOL_CHUNK - 1) / POOL_CHUNK, 128, 0, stream>>>(
        xin16, batch, N, (unsigned int*)pooled);
    head_kernel<<<64, 256, 0, stream>>>(pooled, linW, linb, outW, outb, (float*)d_out);
}